// Round 10
// baseline (123.527 us; speedup 1.0000x reference)
//
#include <hip/hip_runtime.h>
#include <hip/hip_bf16.h>

__device__ __forceinline__ float sigm(float x) { return 1.0f / (1.0f + __expf(-x)); }

// Workspace float layout (all written by frap_setup_all every launch):
#define WS_WCM   0      // [2][20][20] = 800   w_comb * relu(yc) per mask value
#define WS_YA    800    // [60][20]            w_feat[:, :16] . X[key]  (+ b_feat/4)
#define WS_YB    2000   // [60][20]            w_feat[:, 16:] . X[key]  (+ b_feat/4)
#define WS_BCOMB 3200   // 20
#define WS_WFIN  3220   // 20
#define WS_BFIN  3240   // 1
#define WS_KP    4096   // [56*B] u32: packed (kA0,kA1,kB0,kB1) for flat index g

// ---------------- setup: tables (1 block) + KP key-pack (source-ordered) ----
// Grid = 56*B/256 + 1 blocks. Blocks [0, nkp): thread t covers g = p*B + b with
// b lane-adjacent -> feat reads are L1-windowed (4 KB/wave, reused by all 8
// loads). Last block: derived tables (YA/YB/WCM/scalars).
__global__ __launch_bounds__(256) void frap_setup_all(
    const float* __restrict__ feat,
    const float* __restrict__ emb_phase, const float* __restrict__ w_veh,
    const float* __restrict__ b_veh,     const float* __restrict__ w_line,
    const float* __restrict__ b_line,    const float* __restrict__ emb_const,
    const float* __restrict__ w_feat,    const float* __restrict__ b_feat,
    const float* __restrict__ w_const,   const float* __restrict__ b_const,
    const float* __restrict__ w_comb,    const float* __restrict__ b_comb,
    const float* __restrict__ w_final,   const float* __restrict__ b_final,
    float* __restrict__ ws, int B, int nkp)
{
    const int tid = threadIdx.x;
    const unsigned L0T = 0x64204051u, L1T = 0x75316273u;  // PHASE_LANES nibbles

    if ((int)blockIdx.x < nkp) {
        // ---- KP pack: one thread per g = p*B + b (b fast => coalesced) ----
        const int bpp = B >> 8;                    // blocks per p (B/256)
        const int p = blockIdx.x / bpp;            // 0..55, block-uniform
        const int b = (blockIdx.x - p * bpp) * 256 + tid;
        unsigned pi = (unsigned)p / 7u;
        unsigned c7 = (unsigned)p - pi * 7u;
        unsigned pj = c7 + (c7 >= pi ? 1u : 0u);
        int la0 = (L0T >> (pi * 4)) & 15, la1 = (L1T >> (pi * 4)) & 15;
        int lb0 = (L0T >> (pj * 4)) & 15, lb1 = (L1T >> (pj * 4)) & 15;
        const float* row = feat + (size_t)b * 16;
        int kA0 = min(59, max(0, (int)fmaf(row[8 + la0], 2.f, row[la0])));
        int kA1 = min(59, max(0, (int)fmaf(row[8 + la1], 2.f, row[la1])));
        int kB0 = min(59, max(0, (int)fmaf(row[8 + lb0], 2.f, row[lb0])));
        int kB1 = min(59, max(0, (int)fmaf(row[8 + lb1], 2.f, row[lb1])));
        unsigned kp = (unsigned)kA0 | ((unsigned)kA1 << 8) |
                      ((unsigned)kB0 << 16) | ((unsigned)kB1 << 24);
        ((unsigned*)ws)[WS_KP + (size_t)p * B + b] = kp;
        return;
    }

    // ---- derived tables (single block) ----
    __shared__ float s_stage[820];   // [0,128)=w_line [128,768)=w_feat [768,784)=b_line
                                     // [784,788)=w_veh [788,792)=b_veh [792,800)=emb_phase [800,820)=b_feat
    for (int k = tid; k < 128; k += 256) s_stage[k] = w_line[k];
    for (int k = tid; k < 640; k += 256) s_stage[128 + k] = w_feat[k];
    if (tid < 16)                s_stage[768 + tid] = b_line[tid];
    if (tid < 4)                 s_stage[784 + tid] = w_veh[tid];
    if (tid >= 4 && tid < 8)     s_stage[784 + tid] = b_veh[tid - 4];
    if (tid >= 8 && tid < 16)    s_stage[784 + tid] = emb_phase[tid - 8];
    if (tid >= 16 && tid < 36)   s_stage[784 + tid] = b_feat[tid - 16];
    __syncthreads();

    if (tid < 240) {
        int key = tid >> 2, part = tid & 3;
        int veh = key >> 1, pb = key & 1;
        float vf = (float)veh;
        float line[8];
#pragma unroll
        for (int k = 0; k < 4; k++) line[k] = sigm(fmaf(vf, s_stage[784 + k], s_stage[788 + k]));
#pragma unroll
        for (int k = 0; k < 4; k++) line[4 + k] = sigm(s_stage[792 + pb * 4 + k]);
        float X[16];
#pragma unroll
        for (int o = 0; o < 16; o++) {
            float x = s_stage[768 + o];
#pragma unroll
            for (int d = 0; d < 8; d++) x = fmaf(line[d], s_stage[o * 8 + d], x);
            X[o] = fmaxf(x, 0.f);
        }
        int o0 = part * 5;
#pragma unroll
        for (int oo = 0; oo < 5; oo++) {
            int o = o0 + oo;
            float a = 0.25f * s_stage[800 + o];
            float bb = a;
#pragma unroll
            for (int c = 0; c < 16; c++) {
                a  = fmaf(X[c], s_stage[128 + o * 32 + c], a);
                bb = fmaf(X[c], s_stage[128 + o * 32 + 16 + c], bb);
            }
            ws[WS_YA + key * 20 + o] = a;
            ws[WS_YB + key * 20 + o] = bb;
        }
    }

    for (int idx = tid; idx < 800; idx += 256) {
        int m = idx / 400;
        int r = idx - m * 400;
        int q = r / 20;
        int o = r - q * 20;
        float yc = b_const[o];
#pragma unroll
        for (int k = 0; k < 4; k++)
            yc = fmaf(w_const[o * 4 + k], emb_const[m * 4 + k], yc);
        ws[WS_WCM + idx] = w_comb[q * 20 + o] * fmaxf(yc, 0.f);
    }
    if (tid < 20) { ws[WS_BCOMB + tid] = b_comb[tid]; ws[WS_WFIN + tid] = w_final[tid]; }
    if (tid == 0) ws[WS_BFIN] = b_final[0];
}

// ---------------- main ------------------------------------------------------
// 448-thread blocks = 7 waves. Block = (phase i, 64-bp chunk); wave jw handles
// competitor j=jw. One j per thread -> ~50 VGPR live set, no spill. Source
// keys come from ONE packed u32 (WS_KP) instead of 8 scattered feat loads.
// Mask bit is (i,jw)-uniform -> scalar W base; q-loop W rows via uniform s_load.
// Y tables in LDS; partials combined via s_part in j-order (reference order).
__global__ __launch_bounds__(448, 4) void frap_main(
    const int* __restrict__ cmask,
    const float* __restrict__ ws, float* __restrict__ out, int B)
{
    __shared__ __align__(16) float s_y[2400];   // [0,1200)=YA  [1200,2400)=YB
    __shared__ float s_part[448];

    const int tid = threadIdx.x;
    for (int k = tid; k < 600; k += 448)
        ((float4*)s_y)[k] = ((const float4*)(ws + WS_YA))[k];

    const int i = blockIdx.x & 7;              // phase (uniform per block)
    const int chunk = blockIdx.x >> 3;
    const int lane = tid & 63;
    const int jw = __builtin_amdgcn_readfirstlane(tid >> 6);   // 0..6, scalar
    const int bp = (chunk << 6) + lane;
    const bool valid = bp < B;
    const int bpc = valid ? bp : 0;

    const int mbit = __builtin_amdgcn_readfirstlane(cmask[i * 7 + jw]) & 1;
    const float* wbase = ws + WS_WCM + (mbit ? 400 : 0);
    __syncthreads();

    // flat source index g = 56*bp + 7*i + jw ; KP[g] holds the 4 packed keys
    const unsigned g = 56u * (unsigned)bpc + 7u * (unsigned)i + (unsigned)jw;
    const unsigned kp = ((const unsigned*)ws)[WS_KP + g];
    const int kA0 = kp & 255, kA1 = (kp >> 8) & 255;
    const int kB0 = (kp >> 16) & 255, kB1 = (kp >> 24) & 255;

    const float4* A0 = (const float4*)(s_y + kA0 * 20);
    const float4* A1 = (const float4*)(s_y + kA1 * 20);
    const float4* B0 = (const float4*)(s_y + 1200 + kB0 * 20);
    const float4* B1 = (const float4*)(s_y + 1200 + kB1 * 20);

    float xf[20];
#pragma unroll
    for (int r = 0; r < 5; r++) {
        float4 a0 = A0[r], a1 = A1[r], c0 = B0[r], c1 = B1[r];
        xf[4 * r + 0] = fmaxf(a0.x + a1.x + c0.x + c1.x, 0.f);
        xf[4 * r + 1] = fmaxf(a0.y + a1.y + c0.y + c1.y, 0.f);
        xf[4 * r + 2] = fmaxf(a0.z + a1.z + c0.z + c1.z, 0.f);
        xf[4 * r + 3] = fmaxf(a0.w + a1.w + c0.w + c1.w, 0.f);
    }

    float acc = 0.f;
    for (int q = 0; q < 20; q++) {
        const float4* wr = (const float4*)(wbase + q * 20);   // uniform -> s_load
        float4 w0 = wr[0], w1 = wr[1], w2 = wr[2], w3 = wr[3], w4 = wr[4];
        float h = ws[WS_BCOMB + q];
        h = fmaf(w0.x, xf[0],  h); h = fmaf(w0.y, xf[1],  h);
        h = fmaf(w0.z, xf[2],  h); h = fmaf(w0.w, xf[3],  h);
        h = fmaf(w1.x, xf[4],  h); h = fmaf(w1.y, xf[5],  h);
        h = fmaf(w1.z, xf[6],  h); h = fmaf(w1.w, xf[7],  h);
        h = fmaf(w2.x, xf[8],  h); h = fmaf(w2.y, xf[9],  h);
        h = fmaf(w2.z, xf[10], h); h = fmaf(w2.w, xf[11], h);
        h = fmaf(w3.x, xf[12], h); h = fmaf(w3.y, xf[13], h);
        h = fmaf(w3.z, xf[14], h); h = fmaf(w3.w, xf[15], h);
        h = fmaf(w4.x, xf[16], h); h = fmaf(w4.y, xf[17], h);
        h = fmaf(w4.z, xf[18], h); h = fmaf(w4.w, xf[19], h);
        acc = fmaf(ws[WS_WFIN + q], fmaxf(h, 0.f), acc);
    }
    float val = fmaxf(acc + ws[WS_BFIN], 0.f);

    s_part[tid] = val;
    __syncthreads();
    if (jw == 0 && valid) {
        float total = val;                     // j = 0
#pragma unroll
        for (int w = 1; w < 7; w++)            // j = 1..6 in order
            total += s_part[lane + (w << 6)];
        out[(size_t)bp * 8 + i] = total;
    }
}

extern "C" void kernel_launch(void* const* d_in, const int* in_sizes, int n_in,
                              void* d_out, int out_size, void* d_ws, size_t ws_size,
                              hipStream_t stream) {
    const float* feat      = (const float*)d_in[0];
    const float* emb_phase = (const float*)d_in[1];
    const float* w_veh     = (const float*)d_in[2];
    const float* b_veh     = (const float*)d_in[3];
    const float* w_line    = (const float*)d_in[4];
    const float* b_line    = (const float*)d_in[5];
    const float* emb_const = (const float*)d_in[6];
    const float* w_feat    = (const float*)d_in[7];
    const float* b_feat    = (const float*)d_in[8];
    const float* w_const   = (const float*)d_in[9];
    const float* b_const   = (const float*)d_in[10];
    const float* w_comb    = (const float*)d_in[11];
    const float* b_comb    = (const float*)d_in[12];
    const float* w_final   = (const float*)d_in[13];
    const float* b_final   = (const float*)d_in[14];
    const int*   cmask     = (const int*)d_in[15];

    int B = in_sizes[0] / 16;                 // 16384 (power of two)
    float* ws = (float*)d_ws;

    int nkp = 56 * (B >> 8);                  // KP blocks (3584)
    frap_setup_all<<<nkp + 1, 256, 0, stream>>>(feat, emb_phase, w_veh, b_veh,
                                                w_line, b_line, emb_const,
                                                w_feat, b_feat, w_const,
                                                b_const, w_comb, b_comb,
                                                w_final, b_final, ws, B, nkp);
    int blocks = 8 * ((B + 63) / 64);         // 2048
    frap_main<<<blocks, 448, 0, stream>>>(cmask, ws, (float*)d_out, B);
}